// Round 1
// baseline (402.891 us; speedup 1.0000x reference)
//
#include <hip/hip_runtime.h>
#include <hip/hip_bf16.h>

typedef __hip_bfloat16 bf16;

// Dims
constexpr int cD0 = 24,  cH0 = 64,  cW0 = 128;   // cv1 / x1 spatial
constexpr int cD1 = 48,  cH1 = 128, cW1 = 256;   // x2 / cv0 / x3 spatial
constexpr int cD2 = 96,  cH2 = 256, cW2 = 512;   // cost / out spatial
constexpr size_t PL0 = (size_t)cD0 * cH0 * cW0;  // 196608
constexpr size_t PL1 = (size_t)cD1 * cH1 * cW1;  // 1572864
constexpr size_t PL2 = (size_t)cD2 * cH2 * cW2;  // 12582912

__device__ __forceinline__ float b2f(bf16 v) { return __bfloat162float(v); }
__device__ __forceinline__ bf16  f2b(float v) { return __float2bfloat16(v); }
__device__ __forceinline__ float lrelu(float v) { return v >= 0.f ? v : 0.01f * v; }
__device__ __forceinline__ float us2f(ushort u) { return __uint_as_float(((uint)u) << 16); }
__device__ __forceinline__ ushort f2us(float v) { return __bfloat16_as_ushort(f2b(v)); }

// ---------------- Stage A: x1 = bn_lrelu(deconv(cv1, w0a, s1, pad(1,0,0))) ----
__global__ __launch_bounds__(256) void kA(const float* __restrict__ cv1,
                                          const float* __restrict__ w0a,
                                          const float* __restrict__ g0,
                                          const float* __restrict__ b0,
                                          bf16* __restrict__ x1) {
    __shared__ float lw[3][32][32];   // [u][ci][co] — all lanes read same addr (broadcast)
    __shared__ float lsc[32], lbi[32];
    const int tid = threadIdx.x;
    for (int i = tid; i < 32 * 32 * 3; i += 256) {
        int ci = i / 96, r = i - ci * 96, co = r / 3, u = r - co * 3;
        lw[u][ci][co] = w0a[i];
    }
    if (tid < 32) {
        lsc[tid] = g0[tid] * (1.0f / sqrtf(1.0f + 1e-5f));
        lbi[tid] = b0[tid];
    }
    __syncthreads();

    const int pos = blockIdx.x * 256 + tid;        // 196608 total
    const int x = pos & (cW0 - 1);
    const int y = (pos >> 7) & (cH0 - 1);
    const int z = pos >> 13;

    float acc[32];
    #pragma unroll
    for (int co = 0; co < 32; ++co) acc[co] = 0.f;

    #pragma unroll
    for (int u = 0; u < 3; ++u) {
        const int zi = z + 1 - u;
        if (zi < 0 || zi >= cD0) continue;
        const float* src = cv1 + (size_t)(zi * cH0 + y) * cW0 + x;
        for (int ci = 0; ci < 32; ++ci) {
            const float v = src[ci * PL0];
            const float4* wp = (const float4*)&lw[u][ci][0];
            #pragma unroll
            for (int q = 0; q < 8; ++q) {
                float4 wv = wp[q];
                acc[4*q+0] += v * wv.x; acc[4*q+1] += v * wv.y;
                acc[4*q+2] += v * wv.z; acc[4*q+3] += v * wv.w;
            }
        }
    }
    #pragma unroll
    for (int co = 0; co < 32; ++co)
        x1[co * PL0 + (size_t)(z * cH0 + y) * cW0 + x] =
            f2b(lrelu(acc[co] * lsc[co] + lbi[co]));
}

// ---------------- Stage B: x2 = bn_lrelu(deconv(x1, w0b, s2, pad(1,0,0))) ----
// One wave per output row (od,oh). Lane owns iw = 2*lane+{0,1} (one packed uint
// bf16 load per (kd,ci)) and computes BOTH kw outputs -> ow = 4*lane+{0..3},
// stored as one ushort4. 64 VMEM loads/thread (was 256 scalar).
__global__ __launch_bounds__(256) void kB(const bf16* __restrict__ x1,
                                          const float* __restrict__ w0b,
                                          const float* __restrict__ g1,
                                          const float* __restrict__ b1,
                                          bf16* __restrict__ x2) {
    __shared__ float lw[4][2][32][2][16];   // [kd][kh][ci][kw][co]
    __shared__ float lsc[16], lbi[16];
    const int tid = threadIdx.x;
    for (int i = tid; i < 8192; i += 256) {
        // source layout (ci,co,kd,kh,kw): i = ci*256 + co*16 + kd*4 + kh*2 + kw
        int ci = i >> 8, co = (i >> 4) & 15, kd = (i >> 2) & 3, kh = (i >> 1) & 1, kw = i & 1;
        lw[kd][kh][ci][kw][co] = w0b[i];
    }
    if (tid < 16) {
        lsc[tid] = g1[tid] * (1.0f / sqrtf(1.0f + 1e-5f));
        lbi[tid] = b1[tid];
    }
    __syncthreads();

    const int t    = blockIdx.x * 256 + tid;   // 393216 threads (1536 blocks)
    const int lane = t & 63;
    const int row  = t >> 6;                   // 6144 rows = (od,oh)
    const int oh = row & 127, od = row >> 7;
    const int ih = oh >> 1, kh = oh & 1;
    const int p  = (od + 1) & 1;
    const int iw0 = 2 * lane;

    float acc[4][16];                          // [iwq*2+kw][co], ow = 4*lane + idx
    #pragma unroll
    for (int k = 0; k < 4; ++k)
        #pragma unroll
        for (int co = 0; co < 16; ++co) acc[k][co] = 0.f;

    #pragma unroll
    for (int j = 0; j < 2; ++j) {
        const int kd = p + 2 * j;
        const int id = (od + 1 - kd) >> 1;
        if (id < 0 || id >= cD0) continue;
        const bf16* src = x1 + (size_t)(id * cH0 + ih) * cW0 + iw0;
        #pragma unroll 4
        for (int ci = 0; ci < 32; ++ci) {
            const uint pk = *(const uint*)(src + ci * PL0);
            const float v0 = us2f((ushort)(pk & 0xffffu));
            const float v1 = us2f((ushort)(pk >> 16));
            const float4* wp0 = (const float4*)&lw[kd][kh][ci][0][0];
            const float4* wp1 = (const float4*)&lw[kd][kh][ci][1][0];
            #pragma unroll
            for (int q = 0; q < 4; ++q) {
                float4 w0 = wp0[q], w1 = wp1[q];
                acc[0][4*q+0] += v0 * w0.x; acc[0][4*q+1] += v0 * w0.y;
                acc[0][4*q+2] += v0 * w0.z; acc[0][4*q+3] += v0 * w0.w;
                acc[1][4*q+0] += v0 * w1.x; acc[1][4*q+1] += v0 * w1.y;
                acc[1][4*q+2] += v0 * w1.z; acc[1][4*q+3] += v0 * w1.w;
                acc[2][4*q+0] += v1 * w0.x; acc[2][4*q+1] += v1 * w0.y;
                acc[2][4*q+2] += v1 * w0.z; acc[2][4*q+3] += v1 * w0.w;
                acc[3][4*q+0] += v1 * w1.x; acc[3][4*q+1] += v1 * w1.y;
                acc[3][4*q+2] += v1 * w1.z; acc[3][4*q+3] += v1 * w1.w;
            }
        }
    }
    const size_t obase = (size_t)(od * cH1 + oh) * cW1 + 4 * lane;
    #pragma unroll
    for (int co = 0; co < 16; ++co) {
        ushort4 s;
        s.x = f2us(lrelu(acc[0][co] * lsc[co] + lbi[co]));
        s.y = f2us(lrelu(acc[1][co] * lsc[co] + lbi[co]));
        s.z = f2us(lrelu(acc[2][co] * lsc[co] + lbi[co]));
        s.w = f2us(lrelu(acc[3][co] * lsc[co] + lbi[co]));
        *(ushort4*)(x2 + co * PL1 + obase) = s;
    }
}

// ---------------- Stage D: x3 = bn_lrelu(deconv(concat(x2,cv0), w1a, s1, pad(1,0,0)))
// One wave per row (z,y); lane owns x = 4*lane+{0..3}. Per (u,ci): ONE ushort4
// (x2) or float4 (cv0) load feeding 64 FMAs. 96 VMEM loads/thread (was 384).
__global__ __launch_bounds__(256) void kD(const bf16* __restrict__ x2,
                                          const float* __restrict__ cv0,
                                          const float* __restrict__ w1a,
                                          const float* __restrict__ g2,
                                          const float* __restrict__ b2v,
                                          bf16* __restrict__ x3) {
    __shared__ float lw[3][32][16];   // [u][ci][co] — broadcast reads
    __shared__ float lsc[16], lbi[16];
    const int tid = threadIdx.x;
    for (int i = tid; i < 1536; i += 256) {
        int ci = i / 48, r = i - ci * 48, co = r / 3, u = r - co * 3;
        lw[u][ci][co] = w1a[i];
    }
    if (tid < 16) {
        lsc[tid] = g2[tid] * (1.0f / sqrtf(1.0f + 1e-5f));
        lbi[tid] = b2v[tid];
    }
    __syncthreads();

    const int t    = blockIdx.x * 256 + tid;   // 393216 threads (1536 blocks)
    const int lane = t & 63;
    const int row  = t >> 6;                   // 6144 rows = (z,y)
    const int y = row & 127, z = row >> 7;
    const int x0 = 4 * lane;

    float acc[4][16];                          // [x offset][co]
    #pragma unroll
    for (int k = 0; k < 4; ++k)
        #pragma unroll
        for (int co = 0; co < 16; ++co) acc[k][co] = 0.f;

    #pragma unroll
    for (int u = 0; u < 3; ++u) {
        const int zi = z + 1 - u;
        if (zi < 0 || zi >= cD1) continue;
        const size_t base = (size_t)(zi * cH1 + y) * cW1 + x0;
        #pragma unroll 4
        for (int ci = 0; ci < 16; ++ci) {           // channels 0..15 = x2 (bf16)
            const ushort4 pv = *(const ushort4*)(x2 + ci * PL1 + base);
            const float v0 = us2f(pv.x), v1 = us2f(pv.y);
            const float v2 = us2f(pv.z), v3 = us2f(pv.w);
            const float4* wp = (const float4*)&lw[u][ci][0];
            #pragma unroll
            for (int q = 0; q < 4; ++q) {
                float4 wv = wp[q];
                acc[0][4*q+0] += v0 * wv.x; acc[0][4*q+1] += v0 * wv.y;
                acc[0][4*q+2] += v0 * wv.z; acc[0][4*q+3] += v0 * wv.w;
                acc[1][4*q+0] += v1 * wv.x; acc[1][4*q+1] += v1 * wv.y;
                acc[1][4*q+2] += v1 * wv.z; acc[1][4*q+3] += v1 * wv.w;
                acc[2][4*q+0] += v2 * wv.x; acc[2][4*q+1] += v2 * wv.y;
                acc[2][4*q+2] += v2 * wv.z; acc[2][4*q+3] += v2 * wv.w;
                acc[3][4*q+0] += v3 * wv.x; acc[3][4*q+1] += v3 * wv.y;
                acc[3][4*q+2] += v3 * wv.z; acc[3][4*q+3] += v3 * wv.w;
            }
        }
        #pragma unroll 4
        for (int ci = 0; ci < 16; ++ci) {           // channels 16..31 = cv0 (f32)
            const float4 fv = *(const float4*)(cv0 + ci * PL1 + base);
            const float v0 = fv.x, v1 = fv.y, v2 = fv.z, v3 = fv.w;
            const float4* wp = (const float4*)&lw[u][16 + ci][0];
            #pragma unroll
            for (int q = 0; q < 4; ++q) {
                float4 wv = wp[q];
                acc[0][4*q+0] += v0 * wv.x; acc[0][4*q+1] += v0 * wv.y;
                acc[0][4*q+2] += v0 * wv.z; acc[0][4*q+3] += v0 * wv.w;
                acc[1][4*q+0] += v1 * wv.x; acc[1][4*q+1] += v1 * wv.y;
                acc[1][4*q+2] += v1 * wv.z; acc[1][4*q+3] += v1 * wv.w;
                acc[2][4*q+0] += v2 * wv.x; acc[2][4*q+1] += v2 * wv.y;
                acc[2][4*q+2] += v2 * wv.z; acc[2][4*q+3] += v2 * wv.w;
                acc[3][4*q+0] += v3 * wv.x; acc[3][4*q+1] += v3 * wv.y;
                acc[3][4*q+2] += v3 * wv.z; acc[3][4*q+3] += v3 * wv.w;
            }
        }
    }
    const size_t obase = (size_t)(z * cH1 + y) * cW1 + x0;
    #pragma unroll
    for (int co = 0; co < 16; ++co) {
        ushort4 s;
        s.x = f2us(lrelu(acc[0][co] * lsc[co] + lbi[co]));
        s.y = f2us(lrelu(acc[1][co] * lsc[co] + lbi[co]));
        s.z = f2us(lrelu(acc[2][co] * lsc[co] + lbi[co]));
        s.w = f2us(lrelu(acc[3][co] * lsc[co] + lbi[co]));
        *(ushort4*)(x3 + co * PL1 + obase) = s;
    }
}

// ---------------- Stage E: cost = bn_lrelu(deconv(x3, w1b, s2, pad(1,0,0))) ----
// One thread computes the 2x2 (kh,kw) quad for TWO consecutive iw: each x3 load
// is a packed uint (2 bf16) feeding 8 FMAs; stores are 8B ushort4 per oh row.
__global__ __launch_bounds__(256) void kE(const bf16* __restrict__ x3,
                                          const float* __restrict__ w1b,
                                          const float* __restrict__ g3,
                                          const float* __restrict__ b3v,
                                          bf16* __restrict__ cost) {
    __shared__ float lw[256];   // w1b (16,1,4,2,2): i = ci*16 + kd*4 + kh*2 + kw
    const int tid = threadIdx.x;
    lw[tid] = w1b[tid];
    __syncthreads();

    const int t    = blockIdx.x * 256 + tid;   // 1572864 threads (6144 blocks)
    const int lane = t & 63;
    const int rowq = t >> 6;                   // 24576 = 2 * 128 * 96
    const int iwp = lane + 64 * (rowq & 1);    // iw pair index [0,128)
    const int ih  = (rowq >> 1) & 127;
    const int od  = rowq >> 8;
    const int p   = (od + 1) & 1;
    const int iw0 = 2 * iwp;

    float a[2][2][2] = {};                     // [iwq][kh][kw]
    #pragma unroll
    for (int j = 0; j < 2; ++j) {
        const int kd = p + 2 * j;
        const int id = (od + 1 - kd) >> 1;
        if (id < 0 || id >= cD1) continue;
        const size_t base = (size_t)(id * cH1 + ih) * cW1 + iw0;
        #pragma unroll
        for (int ci = 0; ci < 16; ++ci) {
            const uint pk = *(const uint*)(x3 + ci * PL1 + base);
            const float v0 = us2f((ushort)(pk & 0xffffu));
            const float v1 = us2f((ushort)(pk >> 16));
            const float* w = &lw[ci * 16 + kd * 4];
            a[0][0][0] += v0 * w[0]; a[0][0][1] += v0 * w[1];
            a[0][1][0] += v0 * w[2]; a[0][1][1] += v0 * w[3];
            a[1][0][0] += v1 * w[0]; a[1][0][1] += v1 * w[1];
            a[1][1][0] += v1 * w[2]; a[1][1][1] += v1 * w[3];
        }
    }
    const float sc = g3[0] * (1.0f / sqrtf(1.0f + 1e-5f));
    const float bi = b3v[0];
    const size_t ob = (size_t)(od * cH2 + 2 * ih) * cW2 + 4 * iwp;
    ushort4 s;
    s.x = f2us(lrelu(a[0][0][0] * sc + bi));
    s.y = f2us(lrelu(a[0][0][1] * sc + bi));
    s.z = f2us(lrelu(a[1][0][0] * sc + bi));
    s.w = f2us(lrelu(a[1][0][1] * sc + bi));
    *(ushort4*)(cost + ob) = s;
    s.x = f2us(lrelu(a[0][1][0] * sc + bi));
    s.y = f2us(lrelu(a[0][1][1] * sc + bi));
    s.z = f2us(lrelu(a[1][1][0] * sc + bi));
    s.w = f2us(lrelu(a[1][1][1] * sc + bi));
    *(ushort4*)(cost + ob + cW2) = s;
}

// ---------------- Stage F: 9-shift superpixel aggregation --------------------
// out[d,y,x] = Sum_k sp[k,y,x] * cost[d, y-4*(1-r), x-4*(1-c)], OOB -> 0
// Thread owns 4 consecutive x (shifts are +-4, so validity is uniform per
// 4-block and all loads stay vector: float4 sp weights, ushort4 cost) x 4 d.
__global__ __launch_bounds__(256) void kF(const bf16* __restrict__ cost,
                                          const float* __restrict__ sp,
                                          float* __restrict__ out) {
    const int t    = blockIdx.x * 256 + threadIdx.x;  // 786432 threads (3072 blocks)
    const int lane = t & 63;
    const int rowq = t >> 6;                  // 12288 = 2 * 256 * 24
    const int x0 = 4 * (lane + 64 * (rowq & 1));
    const int y  = (rowq >> 1) & 255;
    const int d0 = (rowq >> 9) * 4;
    const size_t plane = (size_t)cH2 * cW2;

    float4 wq[9];
    int cyc[3], cxc[3];
    #pragma unroll
    for (int r = 0; r < 3; ++r) {
        const int cy = y - 4 * (1 - r);
        const bool vy = (cy >= 0) && (cy < cH2);
        cyc[r] = vy ? cy : 0;
        #pragma unroll
        for (int c = 0; c < 3; ++c) {
            const int cx = x0 - 4 * (1 - c);
            const bool vx = (cx >= 0) && (cx < cW2);
            if (r == 0) cxc[c] = vx ? cx : 0;
            if (vy && vx)
                wq[r*3+c] = *(const float4*)(sp + (size_t)(r*3+c) * plane + (size_t)y * cW2 + x0);
            else
                wq[r*3+c] = make_float4(0.f, 0.f, 0.f, 0.f);
        }
    }
    #pragma unroll
    for (int dd = 0; dd < 4; ++dd) {
        const int d = d0 + dd;
        const bf16* cp = cost + (size_t)d * plane;
        float ax = 0.f, ay = 0.f, az = 0.f, aw = 0.f;
        #pragma unroll
        for (int r = 0; r < 3; ++r) {
            const bf16* rp = cp + (size_t)cyc[r] * cW2;
            #pragma unroll
            for (int c = 0; c < 3; ++c) {
                const ushort4 u = *(const ushort4*)(rp + cxc[c]);
                const float4 w = wq[r*3+c];
                ax += w.x * us2f(u.x); ay += w.y * us2f(u.y);
                az += w.z * us2f(u.z); aw += w.w * us2f(u.w);
            }
        }
        float4 o; o.x = ax; o.y = ay; o.z = az; o.w = aw;
        *(float4*)(out + (size_t)d * plane + (size_t)y * cW2 + x0) = o;
    }
}

extern "C" void kernel_launch(void* const* d_in, const int* in_sizes, int n_in,
                              void* d_out, int out_size, void* d_ws, size_t ws_size,
                              hipStream_t stream) {
    const float* cv1 = (const float*)d_in[0];
    const float* cv0 = (const float*)d_in[1];
    const float* sp  = (const float*)d_in[2];
    const float* w0a = (const float*)d_in[3];
    const float* w0b = (const float*)d_in[4];
    const float* w1a = (const float*)d_in[5];
    const float* w1b = (const float*)d_in[6];
    const float* g0  = (const float*)d_in[7];
    const float* g1  = (const float*)d_in[8];
    const float* g2  = (const float*)d_in[9];
    const float* g3  = (const float*)d_in[10];
    const float* b0  = (const float*)d_in[11];
    const float* b1  = (const float*)d_in[12];
    const float* b2  = (const float*)d_in[13];
    const float* b3  = (const float*)d_in[14];

    // Workspace layout (bf16 intermediates, f32 accumulation inside kernels):
    //   x1  @ 0          : 12,582,912 B
    //   x2  @ 12,582,912 : 50,331,648 B   (ends 62,914,560)
    //   x3  @ 62,914,560 : 50,331,648 B   (ends 113,246,208)
    //   cost@ 0          : 25,165,824 B   (aliases dead x1 + part of dead x2)
    char* ws = (char*)d_ws;
    bf16* x1   = (bf16*)(ws);
    bf16* x2   = (bf16*)(ws + 12582912);
    bf16* x3   = (bf16*)(ws + 62914560);
    bf16* cost = (bf16*)(ws);

    kA<<<768,  256, 0, stream>>>(cv1, w0a, g0, b0, x1);
    kB<<<1536, 256, 0, stream>>>(x1, w0b, g1, b1, x2);
    kD<<<1536, 256, 0, stream>>>(x2, cv0, w1a, g2, b2, x3);
    kE<<<6144, 256, 0, stream>>>(x3, w1b, g3, b3, cost);
    kF<<<3072, 256, 0, stream>>>(cost, sp, (float*)d_out);
}

// Round 2
// 383.452 us; speedup vs baseline: 1.0507x; 1.0507x over previous
//
#include <hip/hip_runtime.h>
#include <hip/hip_bf16.h>

typedef __hip_bfloat16 bf16;

// Dims
constexpr int cD0 = 24,  cH0 = 64,  cW0 = 128;   // cv1 / x1 spatial
constexpr int cD1 = 48,  cH1 = 128, cW1 = 256;   // x2 / cv0 / x3 spatial
constexpr int cD2 = 96,  cH2 = 256, cW2 = 512;   // cost / out spatial
constexpr size_t PL0 = (size_t)cD0 * cH0 * cW0;  // 196608
constexpr size_t PL1 = (size_t)cD1 * cH1 * cW1;  // 1572864
constexpr size_t PL2 = (size_t)cD2 * cH2 * cW2;  // 12582912

__device__ __forceinline__ float b2f(bf16 v) { return __bfloat162float(v); }
__device__ __forceinline__ bf16  f2b(float v) { return __float2bfloat16(v); }
__device__ __forceinline__ float lrelu(float v) { return v >= 0.f ? v : 0.01f * v; }
__device__ __forceinline__ float us2f(ushort u) { return __uint_as_float(((uint)u) << 16); }
__device__ __forceinline__ ushort f2us(float v) { return __bfloat16_as_ushort(f2b(v)); }

// ---------------- Stage A: x1 = bn_lrelu(deconv(cv1, w0a, s1, pad(1,0,0))) ----
__global__ __launch_bounds__(256) void kA(const float* __restrict__ cv1,
                                          const float* __restrict__ w0a,
                                          const float* __restrict__ g0,
                                          const float* __restrict__ b0,
                                          bf16* __restrict__ x1) {
    __shared__ float lw[3][32][32];   // [u][ci][co] — all lanes read same addr (broadcast)
    __shared__ float lsc[32], lbi[32];
    const int tid = threadIdx.x;
    for (int i = tid; i < 32 * 32 * 3; i += 256) {
        int ci = i / 96, r = i - ci * 96, co = r / 3, u = r - co * 3;
        lw[u][ci][co] = w0a[i];
    }
    if (tid < 32) {
        lsc[tid] = g0[tid] * (1.0f / sqrtf(1.0f + 1e-5f));
        lbi[tid] = b0[tid];
    }
    __syncthreads();

    const int pos = blockIdx.x * 256 + tid;        // 196608 total
    const int x = pos & (cW0 - 1);
    const int y = (pos >> 7) & (cH0 - 1);
    const int z = pos >> 13;

    float acc[32];
    #pragma unroll
    for (int co = 0; co < 32; ++co) acc[co] = 0.f;

    #pragma unroll
    for (int u = 0; u < 3; ++u) {
        const int zi = z + 1 - u;
        if (zi < 0 || zi >= cD0) continue;
        const float* src = cv1 + (size_t)(zi * cH0 + y) * cW0 + x;
        for (int ci = 0; ci < 32; ++ci) {
            const float v = src[ci * PL0];
            const float4* wp = (const float4*)&lw[u][ci][0];
            #pragma unroll
            for (int q = 0; q < 8; ++q) {
                float4 wv = wp[q];
                acc[4*q+0] += v * wv.x; acc[4*q+1] += v * wv.y;
                acc[4*q+2] += v * wv.z; acc[4*q+3] += v * wv.w;
            }
        }
    }
    #pragma unroll
    for (int co = 0; co < 32; ++co)
        x1[co * PL0 + (size_t)(z * cH0 + y) * cW0 + x] =
            f2b(lrelu(acc[co] * lsc[co] + lbi[co]));
}

// ---------------- Stage B: x2 = bn_lrelu(deconv(x1, w0b, s2, pad(1,0,0))) ----
// Round-0 inner loop (4 ds_read_b128/ci, kw = lane&1, no forced unroll).
// NEW: the 4 waves of a block own 4 consecutive od at the same oh, so the
// x1 rows (id taps, shared across od quad) hit L1/L2 instead of HBM.
__global__ __launch_bounds__(256) void kB(const bf16* __restrict__ x1,
                                          const float* __restrict__ w0b,
                                          const float* __restrict__ g1,
                                          const float* __restrict__ b1,
                                          bf16* __restrict__ x2) {
    __shared__ float lw[4][2][32][2][16];   // [kd][kh][ci][kw][co]
    __shared__ float lsc[16], lbi[16];
    const int tid = threadIdx.x;
    for (int i = tid; i < 8192; i += 256) {
        // source layout (ci,co,kd,kh,kw): i = ci*256 + co*16 + kd*4 + kh*2 + kw
        int ci = i >> 8, co = (i >> 4) & 15, kd = (i >> 2) & 3, kh = (i >> 1) & 1, kw = i & 1;
        lw[kd][kh][ci][kw][co] = w0b[i];
    }
    if (tid < 16) {
        lsc[tid] = g1[tid] * (1.0f / sqrtf(1.0f + 1e-5f));
        lbi[tid] = b1[tid];
    }
    __syncthreads();

    const int t    = blockIdx.x * 256 + tid;   // 393216 threads (1536 blocks)
    const int lane = t & 63;
    const int wv_  = (t >> 6) & 3;             // wave in block -> od sub-index
    const int b_   = t >> 8;                   // 1536 blocks = 128 oh * 12 od-quads
    const int oh = b_ & 127;
    const int od = (b_ >> 7) * 4 + wv_;        // 0..47
    const int ih = oh >> 1, kh = oh & 1;
    const int kw = lane & 1;
    const int p  = (od + 1) & 1;
    const int iwb = lane >> 1;

    float acc[4][16];
    #pragma unroll
    for (int k = 0; k < 4; ++k)
        #pragma unroll
        for (int co = 0; co < 16; ++co) acc[k][co] = 0.f;

    #pragma unroll
    for (int j = 0; j < 2; ++j) {
        const int kd = p + 2 * j;
        const int id = (od + 1 - kd) >> 1;
        if (id < 0 || id >= cD0) continue;
        const bf16* src = x1 + (size_t)(id * cH0 + ih) * cW0 + iwb;
        for (int ci = 0; ci < 32; ++ci) {
            const float v0 = b2f(src[ci * PL0 +  0]);
            const float v1 = b2f(src[ci * PL0 + 32]);
            const float v2 = b2f(src[ci * PL0 + 64]);
            const float v3 = b2f(src[ci * PL0 + 96]);
            const float4* wp = (const float4*)&lw[kd][kh][ci][kw][0];
            #pragma unroll
            for (int q = 0; q < 4; ++q) {
                float4 wv = wp[q];
                acc[0][4*q+0] += v0 * wv.x; acc[0][4*q+1] += v0 * wv.y;
                acc[0][4*q+2] += v0 * wv.z; acc[0][4*q+3] += v0 * wv.w;
                acc[1][4*q+0] += v1 * wv.x; acc[1][4*q+1] += v1 * wv.y;
                acc[1][4*q+2] += v1 * wv.z; acc[1][4*q+3] += v1 * wv.w;
                acc[2][4*q+0] += v2 * wv.x; acc[2][4*q+1] += v2 * wv.y;
                acc[2][4*q+2] += v2 * wv.z; acc[2][4*q+3] += v2 * wv.w;
                acc[3][4*q+0] += v3 * wv.x; acc[3][4*q+1] += v3 * wv.y;
                acc[3][4*q+2] += v3 * wv.z; acc[3][4*q+3] += v3 * wv.w;
            }
        }
    }
    const size_t obase = (size_t)(od * cH1 + oh) * cW1 + lane;
    #pragma unroll
    for (int k = 0; k < 4; ++k)
        #pragma unroll
        for (int co = 0; co < 16; ++co)
            x2[co * PL1 + obase + 64 * k] =
                f2b(lrelu(acc[k][co] * lsc[co] + lbi[co]));
}

// ---------------- Stage D: x3 = bn_lrelu(deconv(concat(x2,cv0), w1a, s1, pad(1,0,0)))
// Lane owns x = 4*lane+{0..3}: one ushort4 (x2) / float4 (cv0) load per (u,ci).
// NEW: the 4 waves of a block own 4 consecutive z at the same y, so the 3
// z-taps (zi in z0-1..z0+4, 6 unique rows for 12 taps) are shared via L1/L2.
__global__ __launch_bounds__(256) void kD(const bf16* __restrict__ x2,
                                          const float* __restrict__ cv0,
                                          const float* __restrict__ w1a,
                                          const float* __restrict__ g2,
                                          const float* __restrict__ b2v,
                                          bf16* __restrict__ x3) {
    __shared__ float lw[3][32][16];   // [u][ci][co] — broadcast reads
    __shared__ float lsc[16], lbi[16];
    const int tid = threadIdx.x;
    for (int i = tid; i < 1536; i += 256) {
        int ci = i / 48, r = i - ci * 48, co = r / 3, u = r - co * 3;
        lw[u][ci][co] = w1a[i];
    }
    if (tid < 16) {
        lsc[tid] = g2[tid] * (1.0f / sqrtf(1.0f + 1e-5f));
        lbi[tid] = b2v[tid];
    }
    __syncthreads();

    const int t    = blockIdx.x * 256 + tid;   // 393216 threads (1536 blocks)
    const int lane = t & 63;
    const int wv_  = (t >> 6) & 3;             // wave in block -> z sub-index
    const int b_   = t >> 8;                   // 1536 blocks = 128 y * 12 z-quads
    const int y = b_ & 127;
    const int z = (b_ >> 7) * 4 + wv_;         // 0..47
    const int x0 = 4 * lane;

    float acc[4][16];                          // [x offset][co]
    #pragma unroll
    for (int k = 0; k < 4; ++k)
        #pragma unroll
        for (int co = 0; co < 16; ++co) acc[k][co] = 0.f;

    #pragma unroll
    for (int u = 0; u < 3; ++u) {
        const int zi = z + 1 - u;
        if (zi < 0 || zi >= cD1) continue;
        const size_t base = (size_t)(zi * cH1 + y) * cW1 + x0;
        #pragma unroll 4
        for (int ci = 0; ci < 16; ++ci) {           // channels 0..15 = x2 (bf16)
            const ushort4 pv = *(const ushort4*)(x2 + ci * PL1 + base);
            const float v0 = us2f(pv.x), v1 = us2f(pv.y);
            const float v2 = us2f(pv.z), v3 = us2f(pv.w);
            const float4* wp = (const float4*)&lw[u][ci][0];
            #pragma unroll
            for (int q = 0; q < 4; ++q) {
                float4 wv = wp[q];
                acc[0][4*q+0] += v0 * wv.x; acc[0][4*q+1] += v0 * wv.y;
                acc[0][4*q+2] += v0 * wv.z; acc[0][4*q+3] += v0 * wv.w;
                acc[1][4*q+0] += v1 * wv.x; acc[1][4*q+1] += v1 * wv.y;
                acc[1][4*q+2] += v1 * wv.z; acc[1][4*q+3] += v1 * wv.w;
                acc[2][4*q+0] += v2 * wv.x; acc[2][4*q+1] += v2 * wv.y;
                acc[2][4*q+2] += v2 * wv.z; acc[2][4*q+3] += v2 * wv.w;
                acc[3][4*q+0] += v3 * wv.x; acc[3][4*q+1] += v3 * wv.y;
                acc[3][4*q+2] += v3 * wv.z; acc[3][4*q+3] += v3 * wv.w;
            }
        }
        #pragma unroll 4
        for (int ci = 0; ci < 16; ++ci) {           // channels 16..31 = cv0 (f32)
            const float4 fv = *(const float4*)(cv0 + ci * PL1 + base);
            const float v0 = fv.x, v1 = fv.y, v2 = fv.z, v3 = fv.w;
            const float4* wp = (const float4*)&lw[u][16 + ci][0];
            #pragma unroll
            for (int q = 0; q < 4; ++q) {
                float4 wv = wp[q];
                acc[0][4*q+0] += v0 * wv.x; acc[0][4*q+1] += v0 * wv.y;
                acc[0][4*q+2] += v0 * wv.z; acc[0][4*q+3] += v0 * wv.w;
                acc[1][4*q+0] += v1 * wv.x; acc[1][4*q+1] += v1 * wv.y;
                acc[1][4*q+2] += v1 * wv.z; acc[1][4*q+3] += v1 * wv.w;
                acc[2][4*q+0] += v2 * wv.x; acc[2][4*q+1] += v2 * wv.y;
                acc[2][4*q+2] += v2 * wv.z; acc[2][4*q+3] += v2 * wv.w;
                acc[3][4*q+0] += v3 * wv.x; acc[3][4*q+1] += v3 * wv.y;
                acc[3][4*q+2] += v3 * wv.z; acc[3][4*q+3] += v3 * wv.w;
            }
        }
    }
    const size_t obase = (size_t)(z * cH1 + y) * cW1 + x0;
    #pragma unroll
    for (int co = 0; co < 16; ++co) {
        ushort4 s;
        s.x = f2us(lrelu(acc[0][co] * lsc[co] + lbi[co]));
        s.y = f2us(lrelu(acc[1][co] * lsc[co] + lbi[co]));
        s.z = f2us(lrelu(acc[2][co] * lsc[co] + lbi[co]));
        s.w = f2us(lrelu(acc[3][co] * lsc[co] + lbi[co]));
        *(ushort4*)(x3 + co * PL1 + obase) = s;
    }
}

// ---------------- Stage E: cost = bn_lrelu(deconv(x3, w1b, s2, pad(1,0,0))) ----
// One thread computes the 2x2 (kh,kw) quad for TWO consecutive iw (uint loads).
// NEW: the 4 waves of a block own 4 consecutive od at the same (ih, iw range),
// so the x3 rows (each id serves 4 od) are shared via L1/L2.
__global__ __launch_bounds__(256) void kE(const bf16* __restrict__ x3,
                                          const float* __restrict__ w1b,
                                          const float* __restrict__ g3,
                                          const float* __restrict__ b3v,
                                          bf16* __restrict__ cost) {
    __shared__ float lw[256];   // w1b (16,1,4,2,2): i = ci*16 + kd*4 + kh*2 + kw
    const int tid = threadIdx.x;
    lw[tid] = w1b[tid];
    __syncthreads();

    const int t    = blockIdx.x * 256 + tid;   // 1572864 threads (6144 blocks)
    const int lane = t & 63;
    const int wv_  = (t >> 6) & 3;             // wave in block -> od sub-index
    const int b_   = t >> 8;                   // 6144 = 2 iw-chunks * 128 ih * 24 od-quads
    const int iwp = lane + 64 * (b_ & 1);      // iw pair index [0,128)
    const int ih  = (b_ >> 1) & 127;
    const int od  = (b_ >> 8) * 4 + wv_;       // 0..95
    const int p   = (od + 1) & 1;
    const int iw0 = 2 * iwp;

    float a[2][2][2] = {};                     // [iwq][kh][kw]
    #pragma unroll
    for (int j = 0; j < 2; ++j) {
        const int kd = p + 2 * j;
        const int id = (od + 1 - kd) >> 1;
        if (id < 0 || id >= cD1) continue;
        const size_t base = (size_t)(id * cH1 + ih) * cW1 + iw0;
        #pragma unroll
        for (int ci = 0; ci < 16; ++ci) {
            const uint pk = *(const uint*)(x3 + ci * PL1 + base);
            const float v0 = us2f((ushort)(pk & 0xffffu));
            const float v1 = us2f((ushort)(pk >> 16));
            const float* w = &lw[ci * 16 + kd * 4];
            a[0][0][0] += v0 * w[0]; a[0][0][1] += v0 * w[1];
            a[0][1][0] += v0 * w[2]; a[0][1][1] += v0 * w[3];
            a[1][0][0] += v1 * w[0]; a[1][0][1] += v1 * w[1];
            a[1][1][0] += v1 * w[2]; a[1][1][1] += v1 * w[3];
        }
    }
    const float sc = g3[0] * (1.0f / sqrtf(1.0f + 1e-5f));
    const float bi = b3v[0];
    const size_t ob = (size_t)(od * cH2 + 2 * ih) * cW2 + 4 * iwp;
    ushort4 s;
    s.x = f2us(lrelu(a[0][0][0] * sc + bi));
    s.y = f2us(lrelu(a[0][0][1] * sc + bi));
    s.z = f2us(lrelu(a[1][0][0] * sc + bi));
    s.w = f2us(lrelu(a[1][0][1] * sc + bi));
    *(ushort4*)(cost + ob) = s;
    s.x = f2us(lrelu(a[0][1][0] * sc + bi));
    s.y = f2us(lrelu(a[0][1][1] * sc + bi));
    s.z = f2us(lrelu(a[1][1][0] * sc + bi));
    s.w = f2us(lrelu(a[1][1][1] * sc + bi));
    *(ushort4*)(cost + ob + cW2) = s;
}

// ---------------- Stage F: 9-shift superpixel aggregation --------------------
// out[d,y,x] = Sum_k sp[k,y,x] * cost[d, y-4*(1-r), x-4*(1-c)], OOB -> 0
// Thread owns 4 consecutive x (shifts are +-4, so validity is uniform per
// 4-block and all loads stay vector: float4 sp weights, ushort4 cost) x 4 d.
__global__ __launch_bounds__(256) void kF(const bf16* __restrict__ cost,
                                          const float* __restrict__ sp,
                                          float* __restrict__ out) {
    const int t    = blockIdx.x * 256 + threadIdx.x;  // 786432 threads (3072 blocks)
    const int lane = t & 63;
    const int rowq = t >> 6;                  // 12288 = 2 * 256 * 24
    const int x0 = 4 * (lane + 64 * (rowq & 1));
    const int y  = (rowq >> 1) & 255;
    const int d0 = (rowq >> 9) * 4;
    const size_t plane = (size_t)cH2 * cW2;

    float4 wq[9];
    int cyc[3], cxc[3];
    #pragma unroll
    for (int r = 0; r < 3; ++r) {
        const int cy = y - 4 * (1 - r);
        const bool vy = (cy >= 0) && (cy < cH2);
        cyc[r] = vy ? cy : 0;
        #pragma unroll
        for (int c = 0; c < 3; ++c) {
            const int cx = x0 - 4 * (1 - c);
            const bool vx = (cx >= 0) && (cx < cW2);
            if (r == 0) cxc[c] = vx ? cx : 0;
            if (vy && vx)
                wq[r*3+c] = *(const float4*)(sp + (size_t)(r*3+c) * plane + (size_t)y * cW2 + x0);
            else
                wq[r*3+c] = make_float4(0.f, 0.f, 0.f, 0.f);
        }
    }
    #pragma unroll
    for (int dd = 0; dd < 4; ++dd) {
        const int d = d0 + dd;
        const bf16* cp = cost + (size_t)d * plane;
        float ax = 0.f, ay = 0.f, az = 0.f, aw = 0.f;
        #pragma unroll
        for (int r = 0; r < 3; ++r) {
            const bf16* rp = cp + (size_t)cyc[r] * cW2;
            #pragma unroll
            for (int c = 0; c < 3; ++c) {
                const ushort4 u = *(const ushort4*)(rp + cxc[c]);
                const float4 w = wq[r*3+c];
                ax += w.x * us2f(u.x); ay += w.y * us2f(u.y);
                az += w.z * us2f(u.z); aw += w.w * us2f(u.w);
            }
        }
        float4 o; o.x = ax; o.y = ay; o.z = az; o.w = aw;
        *(float4*)(out + (size_t)d * plane + (size_t)y * cW2 + x0) = o;
    }
}

extern "C" void kernel_launch(void* const* d_in, const int* in_sizes, int n_in,
                              void* d_out, int out_size, void* d_ws, size_t ws_size,
                              hipStream_t stream) {
    const float* cv1 = (const float*)d_in[0];
    const float* cv0 = (const float*)d_in[1];
    const float* sp  = (const float*)d_in[2];
    const float* w0a = (const float*)d_in[3];
    const float* w0b = (const float*)d_in[4];
    const float* w1a = (const float*)d_in[5];
    const float* w1b = (const float*)d_in[6];
    const float* g0  = (const float*)d_in[7];
    const float* g1  = (const float*)d_in[8];
    const float* g2  = (const float*)d_in[9];
    const float* g3  = (const float*)d_in[10];
    const float* b0  = (const float*)d_in[11];
    const float* b1  = (const float*)d_in[12];
    const float* b2  = (const float*)d_in[13];
    const float* b3  = (const float*)d_in[14];

    // Workspace layout (bf16 intermediates, f32 accumulation inside kernels):
    //   x1  @ 0          : 12,582,912 B
    //   x2  @ 12,582,912 : 50,331,648 B   (ends 62,914,560)
    //   x3  @ 62,914,560 : 50,331,648 B   (ends 113,246,208)
    //   cost@ 0          : 25,165,824 B   (aliases dead x1 + part of dead x2)
    char* ws = (char*)d_ws;
    bf16* x1   = (bf16*)(ws);
    bf16* x2   = (bf16*)(ws + 12582912);
    bf16* x3   = (bf16*)(ws + 62914560);
    bf16* cost = (bf16*)(ws);

    kA<<<768,  256, 0, stream>>>(cv1, w0a, g0, b0, x1);
    kB<<<1536, 256, 0, stream>>>(x1, w0b, g1, b1, x2);
    kD<<<1536, 256, 0, stream>>>(x2, cv0, w1a, g2, b2, x3);
    kE<<<6144, 256, 0, stream>>>(x3, w1b, g3, b3, cost);
    kF<<<3072, 256, 0, stream>>>(cost, sp, (float*)d_out);
}

// Round 3
// 377.964 us; speedup vs baseline: 1.0659x; 1.0145x over previous
//
#include <hip/hip_runtime.h>
#include <hip/hip_bf16.h>

typedef __hip_bfloat16 bf16;

// Dims
constexpr int cD0 = 24,  cH0 = 64,  cW0 = 128;   // cv1 / x1 spatial
constexpr int cD1 = 48,  cH1 = 128, cW1 = 256;   // x2 / cv0 / x3 spatial
constexpr int cD2 = 96,  cH2 = 256, cW2 = 512;   // cost / out spatial
constexpr size_t PL0 = (size_t)cD0 * cH0 * cW0;  // 196608
constexpr size_t PL1 = (size_t)cD1 * cH1 * cW1;  // 1572864
constexpr size_t PL2 = (size_t)cD2 * cH2 * cW2;  // 12582912

__device__ __forceinline__ float b2f(bf16 v) { return __bfloat162float(v); }
__device__ __forceinline__ bf16  f2b(float v) { return __float2bfloat16(v); }
__device__ __forceinline__ float lrelu(float v) { return v >= 0.f ? v : 0.01f * v; }
__device__ __forceinline__ float us2f(ushort u) { return __uint_as_float(((uint)u) << 16); }
__device__ __forceinline__ ushort f2us(float v) { return __bfloat16_as_ushort(f2b(v)); }

// ---------------- Stage A: x1 = bn_lrelu(deconv(cv1, w0a, s1, pad(1,0,0))) ----
__global__ __launch_bounds__(256) void kA(const float* __restrict__ cv1,
                                          const float* __restrict__ w0a,
                                          const float* __restrict__ g0,
                                          const float* __restrict__ b0,
                                          bf16* __restrict__ x1) {
    __shared__ float lw[3][32][32];   // [u][ci][co] — all lanes read same addr (broadcast)
    __shared__ float lsc[32], lbi[32];
    const int tid = threadIdx.x;
    for (int i = tid; i < 32 * 32 * 3; i += 256) {
        int ci = i / 96, r = i - ci * 96, co = r / 3, u = r - co * 3;
        lw[u][ci][co] = w0a[i];
    }
    if (tid < 32) {
        lsc[tid] = g0[tid] * (1.0f / sqrtf(1.0f + 1e-5f));
        lbi[tid] = b0[tid];
    }
    __syncthreads();

    const int pos = blockIdx.x * 256 + tid;        // 196608 total
    const int x = pos & (cW0 - 1);
    const int y = (pos >> 7) & (cH0 - 1);
    const int z = pos >> 13;

    float acc[32];
    #pragma unroll
    for (int co = 0; co < 32; ++co) acc[co] = 0.f;

    #pragma unroll
    for (int u = 0; u < 3; ++u) {
        const int zi = z + 1 - u;
        if (zi < 0 || zi >= cD0) continue;
        const float* src = cv1 + (size_t)(zi * cH0 + y) * cW0 + x;
        for (int ci = 0; ci < 32; ++ci) {
            const float v = src[ci * PL0];
            const float4* wp = (const float4*)&lw[u][ci][0];
            #pragma unroll
            for (int q = 0; q < 8; ++q) {
                float4 wv = wp[q];
                acc[4*q+0] += v * wv.x; acc[4*q+1] += v * wv.y;
                acc[4*q+2] += v * wv.z; acc[4*q+3] += v * wv.w;
            }
        }
    }
    #pragma unroll
    for (int co = 0; co < 32; ++co)
        x1[co * PL0 + (size_t)(z * cH0 + y) * cW0 + x] =
            f2b(lrelu(acc[co] * lsc[co] + lbi[co]));
}

// ---------------- Stage B: x2 = bn_lrelu(deconv(x1, w0b, s2, pad(1,0,0))) ----
// Round-0 inner loop (4 ds_read_b128/ci, kw = lane&1, no forced unroll).
// The 4 waves of a block own 4 consecutive od at the same oh, so the
// x1 rows (id taps, shared across od quad) hit L1/L2 instead of HBM.
__global__ __launch_bounds__(256) void kB(const bf16* __restrict__ x1,
                                          const float* __restrict__ w0b,
                                          const float* __restrict__ g1,
                                          const float* __restrict__ b1,
                                          bf16* __restrict__ x2) {
    __shared__ float lw[4][2][32][2][16];   // [kd][kh][ci][kw][co]
    __shared__ float lsc[16], lbi[16];
    const int tid = threadIdx.x;
    for (int i = tid; i < 8192; i += 256) {
        // source layout (ci,co,kd,kh,kw): i = ci*256 + co*16 + kd*4 + kh*2 + kw
        int ci = i >> 8, co = (i >> 4) & 15, kd = (i >> 2) & 3, kh = (i >> 1) & 1, kw = i & 1;
        lw[kd][kh][ci][kw][co] = w0b[i];
    }
    if (tid < 16) {
        lsc[tid] = g1[tid] * (1.0f / sqrtf(1.0f + 1e-5f));
        lbi[tid] = b1[tid];
    }
    __syncthreads();

    const int t    = blockIdx.x * 256 + tid;   // 393216 threads (1536 blocks)
    const int lane = t & 63;
    const int wv_  = (t >> 6) & 3;             // wave in block -> od sub-index
    const int b_   = t >> 8;                   // 1536 blocks = 128 oh * 12 od-quads
    const int oh = b_ & 127;
    const int od = (b_ >> 7) * 4 + wv_;        // 0..47
    const int ih = oh >> 1, kh = oh & 1;
    const int kw = lane & 1;
    const int p  = (od + 1) & 1;
    const int iwb = lane >> 1;

    float acc[4][16];
    #pragma unroll
    for (int k = 0; k < 4; ++k)
        #pragma unroll
        for (int co = 0; co < 16; ++co) acc[k][co] = 0.f;

    #pragma unroll
    for (int j = 0; j < 2; ++j) {
        const int kd = p + 2 * j;
        const int id = (od + 1 - kd) >> 1;
        if (id < 0 || id >= cD0) continue;
        const bf16* src = x1 + (size_t)(id * cH0 + ih) * cW0 + iwb;
        for (int ci = 0; ci < 32; ++ci) {
            const float v0 = b2f(src[ci * PL0 +  0]);
            const float v1 = b2f(src[ci * PL0 + 32]);
            const float v2 = b2f(src[ci * PL0 + 64]);
            const float v3 = b2f(src[ci * PL0 + 96]);
            const float4* wp = (const float4*)&lw[kd][kh][ci][kw][0];
            #pragma unroll
            for (int q = 0; q < 4; ++q) {
                float4 wv = wp[q];
                acc[0][4*q+0] += v0 * wv.x; acc[0][4*q+1] += v0 * wv.y;
                acc[0][4*q+2] += v0 * wv.z; acc[0][4*q+3] += v0 * wv.w;
                acc[1][4*q+0] += v1 * wv.x; acc[1][4*q+1] += v1 * wv.y;
                acc[1][4*q+2] += v1 * wv.z; acc[1][4*q+3] += v1 * wv.w;
                acc[2][4*q+0] += v2 * wv.x; acc[2][4*q+1] += v2 * wv.y;
                acc[2][4*q+2] += v2 * wv.z; acc[2][4*q+3] += v2 * wv.w;
                acc[3][4*q+0] += v3 * wv.x; acc[3][4*q+1] += v3 * wv.y;
                acc[3][4*q+2] += v3 * wv.z; acc[3][4*q+3] += v3 * wv.w;
            }
        }
    }
    const size_t obase = (size_t)(od * cH1 + oh) * cW1 + lane;
    #pragma unroll
    for (int k = 0; k < 4; ++k)
        #pragma unroll
        for (int co = 0; co < 16; ++co)
            x2[co * PL1 + obase + 64 * k] =
                f2b(lrelu(acc[k][co] * lsc[co] + lbi[co]));
}

// ---------------- Stage D: x3 = bn_lrelu(deconv(concat(x2,cv0), w1a, s1, pad(1,0,0)))
// NEW this round: thread owns 2 x positions x 16 co (acc 32 regs) -> 3072
// blocks (12/CU requested) for latency hiding; block = z-quad at fixed (y,h);
// block order zq-fastest + XCD-chunked bijective swizzle so the 3 z-tap
// consumers of each input row are temporally adjacent on the same XCD L2.
__global__ __launch_bounds__(256) void kD(const bf16* __restrict__ x2,
                                          const float* __restrict__ cv0,
                                          const float* __restrict__ w1a,
                                          const float* __restrict__ g2,
                                          const float* __restrict__ b2v,
                                          bf16* __restrict__ x3) {
    __shared__ float lw[3][32][16];   // [u][ci][co] — broadcast reads
    __shared__ float lsc[16], lbi[16];
    const int tid = threadIdx.x;
    for (int i = tid; i < 1536; i += 256) {
        int ci = i / 48, r = i - ci * 48, co = r / 3, u = r - co * 3;
        lw[u][ci][co] = w1a[i];
    }
    if (tid < 16) {
        lsc[tid] = g2[tid] * (1.0f / sqrtf(1.0f + 1e-5f));
        lbi[tid] = b2v[tid];
    }
    __syncthreads();

    // 3072 blocks. XCD-chunked swizzle (3072 % 8 == 0 -> bijective):
    // XCD k owns contiguous b_ range [k*384, (k+1)*384).
    const int bid = blockIdx.x;
    const int b_  = (bid & 7) * 384 + (bid >> 3);
    // b_ fields, zq fastest: b_ = (y*2 + h)*12 + zq
    const int zq = b_ % 12;
    const int yh = b_ / 12;                    // 0..255
    const int h  = yh & 1;
    const int y  = yh >> 1;
    const int lane = tid & 63;
    const int wv_  = tid >> 6;                 // wave -> z sub-index
    const int z  = zq * 4 + wv_;               // 0..47
    const int x0 = h * 128 + 2 * lane;         // 2 consecutive x per thread

    float acc[2][16];                          // [x offset][co]
    #pragma unroll
    for (int k = 0; k < 2; ++k)
        #pragma unroll
        for (int co = 0; co < 16; ++co) acc[k][co] = 0.f;

    #pragma unroll
    for (int u = 0; u < 3; ++u) {
        const int zi = z + 1 - u;
        if (zi < 0 || zi >= cD1) continue;
        const size_t base = (size_t)(zi * cH1 + y) * cW1 + x0;
        #pragma unroll 4
        for (int ci = 0; ci < 16; ++ci) {           // channels 0..15 = x2 (bf16)
            const uint pk = *(const uint*)(x2 + ci * PL1 + base);
            const float v0 = us2f((ushort)(pk & 0xffffu));
            const float v1 = us2f((ushort)(pk >> 16));
            const float4* wp = (const float4*)&lw[u][ci][0];
            #pragma unroll
            for (int q = 0; q < 4; ++q) {
                float4 wv = wp[q];
                acc[0][4*q+0] += v0 * wv.x; acc[0][4*q+1] += v0 * wv.y;
                acc[0][4*q+2] += v0 * wv.z; acc[0][4*q+3] += v0 * wv.w;
                acc[1][4*q+0] += v1 * wv.x; acc[1][4*q+1] += v1 * wv.y;
                acc[1][4*q+2] += v1 * wv.z; acc[1][4*q+3] += v1 * wv.w;
            }
        }
        #pragma unroll 4
        for (int ci = 0; ci < 16; ++ci) {           // channels 16..31 = cv0 (f32)
            const float2 fv = *(const float2*)(cv0 + ci * PL1 + base);
            const float v0 = fv.x, v1 = fv.y;
            const float4* wp = (const float4*)&lw[u][16 + ci][0];
            #pragma unroll
            for (int q = 0; q < 4; ++q) {
                float4 wv = wp[q];
                acc[0][4*q+0] += v0 * wv.x; acc[0][4*q+1] += v0 * wv.y;
                acc[0][4*q+2] += v0 * wv.z; acc[0][4*q+3] += v0 * wv.w;
                acc[1][4*q+0] += v1 * wv.x; acc[1][4*q+1] += v1 * wv.y;
                acc[1][4*q+2] += v1 * wv.z; acc[1][4*q+3] += v1 * wv.w;
            }
        }
    }
    const size_t obase = (size_t)(z * cH1 + y) * cW1 + x0;
    #pragma unroll
    for (int co = 0; co < 16; ++co) {
        union { uint u32; ushort s[2]; } pk;
        pk.s[0] = f2us(lrelu(acc[0][co] * lsc[co] + lbi[co]));
        pk.s[1] = f2us(lrelu(acc[1][co] * lsc[co] + lbi[co]));
        *(uint*)(x3 + co * PL1 + obase) = pk.u32;
    }
}

// ---------------- Stage E: cost = bn_lrelu(deconv(x3, w1b, s2, pad(1,0,0))) ----
// One thread computes the 2x2 (kh,kw) quad for TWO consecutive iw (uint loads).
// The 4 waves of a block own 4 consecutive od at the same (ih, iw range),
// so the x3 rows (each id serves 4 od) are shared via L1/L2.
__global__ __launch_bounds__(256) void kE(const bf16* __restrict__ x3,
                                          const float* __restrict__ w1b,
                                          const float* __restrict__ g3,
                                          const float* __restrict__ b3v,
                                          bf16* __restrict__ cost) {
    __shared__ float lw[256];   // w1b (16,1,4,2,2): i = ci*16 + kd*4 + kh*2 + kw
    const int tid = threadIdx.x;
    lw[tid] = w1b[tid];
    __syncthreads();

    const int t    = blockIdx.x * 256 + tid;   // 1572864 threads (6144 blocks)
    const int lane = t & 63;
    const int wv_  = (t >> 6) & 3;             // wave in block -> od sub-index
    const int b_   = t >> 8;                   // 6144 = 2 iw-chunks * 128 ih * 24 od-quads
    const int iwp = lane + 64 * (b_ & 1);      // iw pair index [0,128)
    const int ih  = (b_ >> 1) & 127;
    const int od  = (b_ >> 8) * 4 + wv_;       // 0..95
    const int p   = (od + 1) & 1;
    const int iw0 = 2 * iwp;

    float a[2][2][2] = {};                     // [iwq][kh][kw]
    #pragma unroll
    for (int j = 0; j < 2; ++j) {
        const int kd = p + 2 * j;
        const int id = (od + 1 - kd) >> 1;
        if (id < 0 || id >= cD1) continue;
        const size_t base = (size_t)(id * cH1 + ih) * cW1 + iw0;
        #pragma unroll
        for (int ci = 0; ci < 16; ++ci) {
            const uint pk = *(const uint*)(x3 + ci * PL1 + base);
            const float v0 = us2f((ushort)(pk & 0xffffu));
            const float v1 = us2f((ushort)(pk >> 16));
            const float* w = &lw[ci * 16 + kd * 4];
            a[0][0][0] += v0 * w[0]; a[0][0][1] += v0 * w[1];
            a[0][1][0] += v0 * w[2]; a[0][1][1] += v0 * w[3];
            a[1][0][0] += v1 * w[0]; a[1][0][1] += v1 * w[1];
            a[1][1][0] += v1 * w[2]; a[1][1][1] += v1 * w[3];
        }
    }
    const float sc = g3[0] * (1.0f / sqrtf(1.0f + 1e-5f));
    const float bi = b3v[0];
    const size_t ob = (size_t)(od * cH2 + 2 * ih) * cW2 + 4 * iwp;
    ushort4 s;
    s.x = f2us(lrelu(a[0][0][0] * sc + bi));
    s.y = f2us(lrelu(a[0][0][1] * sc + bi));
    s.z = f2us(lrelu(a[1][0][0] * sc + bi));
    s.w = f2us(lrelu(a[1][0][1] * sc + bi));
    *(ushort4*)(cost + ob) = s;
    s.x = f2us(lrelu(a[0][1][0] * sc + bi));
    s.y = f2us(lrelu(a[0][1][1] * sc + bi));
    s.z = f2us(lrelu(a[1][1][0] * sc + bi));
    s.w = f2us(lrelu(a[1][1][1] * sc + bi));
    *(ushort4*)(cost + ob + cW2) = s;
}

// ---------------- Stage F: 9-shift superpixel aggregation --------------------
// out[d,y,x] = Sum_k sp[k,y,x] * cost[d, y-4*(1-r), x-4*(1-c)], OOB -> 0
// Thread owns 4 consecutive x (shifts are +-4, so validity is uniform per
// 4-block and all loads stay vector: float4 sp weights, ushort4 cost) x 4 d.
__global__ __launch_bounds__(256) void kF(const bf16* __restrict__ cost,
                                          const float* __restrict__ sp,
                                          float* __restrict__ out) {
    const int t    = blockIdx.x * 256 + threadIdx.x;  // 786432 threads (3072 blocks)
    const int lane = t & 63;
    const int rowq = t >> 6;                  // 12288 = 2 * 256 * 24
    const int x0 = 4 * (lane + 64 * (rowq & 1));
    const int y  = (rowq >> 1) & 255;
    const int d0 = (rowq >> 9) * 4;
    const size_t plane = (size_t)cH2 * cW2;

    float4 wq[9];
    int cyc[3], cxc[3];
    #pragma unroll
    for (int r = 0; r < 3; ++r) {
        const int cy = y - 4 * (1 - r);
        const bool vy = (cy >= 0) && (cy < cH2);
        cyc[r] = vy ? cy : 0;
        #pragma unroll
        for (int c = 0; c < 3; ++c) {
            const int cx = x0 - 4 * (1 - c);
            const bool vx = (cx >= 0) && (cx < cW2);
            if (r == 0) cxc[c] = vx ? cx : 0;
            if (vy && vx)
                wq[r*3+c] = *(const float4*)(sp + (size_t)(r*3+c) * plane + (size_t)y * cW2 + x0);
            else
                wq[r*3+c] = make_float4(0.f, 0.f, 0.f, 0.f);
        }
    }
    #pragma unroll
    for (int dd = 0; dd < 4; ++dd) {
        const int d = d0 + dd;
        const bf16* cp = cost + (size_t)d * plane;
        float ax = 0.f, ay = 0.f, az = 0.f, aw = 0.f;
        #pragma unroll
        for (int r = 0; r < 3; ++r) {
            const bf16* rp = cp + (size_t)cyc[r] * cW2;
            #pragma unroll
            for (int c = 0; c < 3; ++c) {
                const ushort4 u = *(const ushort4*)(rp + cxc[c]);
                const float4 w = wq[r*3+c];
                ax += w.x * us2f(u.x); ay += w.y * us2f(u.y);
                az += w.z * us2f(u.z); aw += w.w * us2f(u.w);
            }
        }
        float4 o; o.x = ax; o.y = ay; o.z = az; o.w = aw;
        *(float4*)(out + (size_t)d * plane + (size_t)y * cW2 + x0) = o;
    }
}

extern "C" void kernel_launch(void* const* d_in, const int* in_sizes, int n_in,
                              void* d_out, int out_size, void* d_ws, size_t ws_size,
                              hipStream_t stream) {
    const float* cv1 = (const float*)d_in[0];
    const float* cv0 = (const float*)d_in[1];
    const float* sp  = (const float*)d_in[2];
    const float* w0a = (const float*)d_in[3];
    const float* w0b = (const float*)d_in[4];
    const float* w1a = (const float*)d_in[5];
    const float* w1b = (const float*)d_in[6];
    const float* g0  = (const float*)d_in[7];
    const float* g1  = (const float*)d_in[8];
    const float* g2  = (const float*)d_in[9];
    const float* g3  = (const float*)d_in[10];
    const float* b0  = (const float*)d_in[11];
    const float* b1  = (const float*)d_in[12];
    const float* b2  = (const float*)d_in[13];
    const float* b3  = (const float*)d_in[14];

    // Workspace layout (bf16 intermediates, f32 accumulation inside kernels):
    //   x1  @ 0          : 12,582,912 B
    //   x2  @ 12,582,912 : 50,331,648 B   (ends 62,914,560)
    //   x3  @ 62,914,560 : 50,331,648 B   (ends 113,246,208)
    //   cost@ 0          : 25,165,824 B   (aliases dead x1 + part of dead x2)
    char* ws = (char*)d_ws;
    bf16* x1   = (bf16*)(ws);
    bf16* x2   = (bf16*)(ws + 12582912);
    bf16* x3   = (bf16*)(ws + 62914560);
    bf16* cost = (bf16*)(ws);

    kA<<<768,  256, 0, stream>>>(cv1, w0a, g0, b0, x1);
    kB<<<1536, 256, 0, stream>>>(x1, w0b, g1, b1, x2);
    kD<<<3072, 256, 0, stream>>>(x2, cv0, w1a, g2, b2, x3);
    kE<<<6144, 256, 0, stream>>>(x3, w1b, g3, b3, cost);
    kF<<<3072, 256, 0, stream>>>(cost, sp, (float*)d_out);
}